// Round 1
// 111.870 us; speedup vs baseline: 1.0090x; 1.0090x over previous
//
#include <hip/hip_runtime.h>

// Always (smoothed-min sliding window, W=16) over [B,T,D] fp32, two traces.
// out[b,t,d] = -log( sum_{j=0..15} exp(-5 x[b, max(t-15+j,0), d]) ) / 5
//
// R7 = R6 + asm-liveness fence on all 32 load results.
// R6's sched_barrier did NOT stick: VGPR_Count=72 proves the allocator
// re-sank the loads into the compute (only ~15 float4 ever in flight ->
// loads execute as serialized latency rounds; VALUBusy 16%, HBM 27%,
// everything idle = latency-bound). The empty asm "+v" uses on every
// component force all 128 payload VGPRs simultaneously live at the fence:
// the compiler MUST issue all 32 dwordx4 before any compute, and drains
// them in consumption order (h0..h15, a0..a15). Target VGPR ~150 < 168
// cap from launch_bounds(256,3).

#define TT     8192
#define DD     64
#define BB     16
#define LCH    16            // t-steps per chunk (one aligned block)
#define CHUNKS (TT / LCH)    // 512

typedef float vfloat4 __attribute__((ext_vector_type(4)));

__device__ __forceinline__ float4 exp4n(float4 v) {
    float4 r;
    r.x = __expf(-5.0f * v.x);
    r.y = __expf(-5.0f * v.y);
    r.z = __expf(-5.0f * v.z);
    r.w = __expf(-5.0f * v.w);
    return r;
}
__device__ __forceinline__ float4 add4(float4 a, float4 b) {
    return make_float4(a.x + b.x, a.y + b.y, a.z + b.z, a.w + b.w);
}
__device__ __forceinline__ vfloat4 mlog4(float4 v) {
    vfloat4 r;
    r.x = -0.2f * __logf(v.x);
    r.y = -0.2f * __logf(v.y);
    r.z = -0.2f * __logf(v.z);
    r.w = -0.2f * __logf(v.w);
    return r;
}

// Keep a loaded float4 alive-in-registers at this program point. An asm
// input/output cannot be deleted, duplicated, or sunk -- this pins the
// load ABOVE the fence and its 4 VGPRs live AT the fence.
#define KEEP4(v) asm volatile("" : "+v"((v).x), "+v"((v).y), "+v"((v).z), "+v"((v).w))

__global__ __launch_bounds__(256, 3) void always_minish_v7(
    const float* __restrict__ lower,
    const float* __restrict__ upper,
    float* __restrict__ out)
{
    const int lane  = threadIdx.x & 63;
    const int wv    = (blockIdx.x << 2) | (threadIdx.x >> 6);
    const int dq    = lane & 15;           // d-quad: channels 4*dq .. 4*dq+3
    const int sq    = lane >> 4;           // seq within group of 4
    const int g     = wv >> 9;             // seq group 0..7
    const int chunk = wv & (CHUNKS - 1);   // 0..511
    const int seq   = (g << 2) | sq;       // 0..31 = trace*16 + b
    const int tr    = seq >> 4;
    const int b     = seq & 15;

    const float* __restrict__ src =
        (tr ? upper : lower) + (size_t)b * TT * DD + dq * 4;
    float* __restrict__ dst = out + (size_t)seq * TT * DD + dq * 4;

    const int t0 = chunk * LCH;

    // ---- Load phase: 32 independent dwordx4, ALL issued before compute ----
    float4 h[16], a[16];
    #pragma unroll
    for (int j = 0; j < 16; ++j) {
        int t = t0 - 16 + j;               // clamped halo = h0 broadcast pad
        if (t < 0) t = 0;
        h[j] = *(const float4*)(src + (size_t)t * DD);
    }
    #pragma unroll
    for (int k = 0; k < 16; ++k)
        a[k] = *(const float4*)(src + (size_t)(t0 + k) * DD);

    // Ordering fence (keeps loads textually above)...
    __builtin_amdgcn_sched_barrier(0);
    // ...and the liveness fence the allocator cannot undo: all 32 results
    // (128 VGPRs) are forced live here, so all 32 loads are in flight.
    #pragma unroll
    for (int j = 0; j < 16; ++j) KEEP4(h[j]);
    #pragma unroll
    for (int k = 0; k < 16; ++k) KEEP4(a[k]);
    __builtin_amdgcn_sched_barrier(0);

    // ---- exp(-5x) ----
    #pragma unroll
    for (int j = 0; j < 16; ++j) h[j] = exp4n(h[j]);
    #pragma unroll
    for (int k = 0; k < 16; ++k) a[k] = exp4n(a[k]);

    // ---- suffix sums of halo: h[j] = sum h[j..15] ----
    #pragma unroll
    for (int j = 14; j >= 0; --j) h[j] = add4(h[j], h[j + 1]);

    // ---- out[t0+k] = -log(h_suffix[k+1] + prefix_a[k]) / 5, NT stores ----
    float4 p = make_float4(0.f, 0.f, 0.f, 0.f);
    #pragma unroll
    for (int k = 0; k < 16; ++k) {
        p = add4(p, a[k]);
        const float4 w = (k < 15) ? add4(h[k + 1], p) : p;
        __builtin_nontemporal_store(mlog4(w),
                                    (vfloat4*)(dst + (size_t)(t0 + k) * DD));
    }
}

extern "C" void kernel_launch(void* const* d_in, const int* in_sizes, int n_in,
                              void* d_out, int out_size, void* d_ws, size_t ws_size,
                              hipStream_t stream)
{
    const float* lower = (const float*)d_in[0];
    const float* upper = (const float*)d_in[1];
    float* out = (float*)d_out;

    // waves = 8 seq-groups * 512 chunks = 4096 -> 1024 blocks of 4 waves
    dim3 grid(1024), block(256);
    hipLaunchKernelGGL(always_minish_v7, grid, block, 0, stream,
                       lower, upper, out);
}

// Round 2
// 111.276 us; speedup vs baseline: 1.0144x; 1.0053x over previous
//
#include <hip/hip_runtime.h>

// Always (smoothed-min sliding window, W=16) over [B,T,D] fp32, two traces.
// out[b,t,d] = -log( sum_{j=0..15} exp(-5 x[b, max(t-15+j,0), d]) ) / 5
//
// R8: strip-walk restructure. R7 post-mortem: VGPR=80 proved the 32-deep
// load burst never materialized (needs 128+ live); steady-state kernel
// ~43us with VALUBusy 22%, HBM 31%, occupancy 23% -- nothing saturated.
// Diagnosis: (a) each old wave touched 8 distant 4-8KB address streams
// (4 seqs x read+write+halo) -> ~32K concurrent 256B streams = DRAM
// row thrash; (b) every wave re-loaded AND re-exp'd its 16-step halo
// (2x read requests, 2x transcendental work); (c) burst-load/compute/die
// lifecycle gives bursty memory demand.
// New shape: wave = one (trace,b) seq, lane = channel d (dword loads,
// perfectly coalesced 256B/instr), walks SLEN=64 consecutive t in 4
// blocks of 16 with a 4-buffer rotation:
//   - exp'd block i IS block i+1's halo (zero halo reload / re-exp)
//   - block i+2's loads issue during block i's compute (continuous MLP)
//   - one contiguous 16KB read stream + one 16KB write stream per wave
// Same 4096 waves. Suffix(prev) + prefix(cur) sliding-window sum as before.

#define TT     8192
#define DD     64
#define STRIPS 128           // strips per seq
#define SLEN   (TT / STRIPS) // 64 t-steps per wave

// One 16-step block: PREV holds exp(-5x) of the previous 16 steps,
// CUR holds raw x of this block. Computes outputs for t = tb..tb+15.
// Destroys PREV (suffix in place); leaves CUR exp'd (= next PREV).
#define BLOCK(PREV, CUR, tb)                                              \
    {                                                                     \
        _Pragma("unroll")                                                 \
        for (int k = 0; k < 16; ++k) CUR[k] = __expf(-5.0f * CUR[k]);     \
        _Pragma("unroll")                                                 \
        for (int j = 14; j >= 0; --j) PREV[j] += PREV[j + 1];             \
        float p = 0.f;                                                    \
        _Pragma("unroll")                                                 \
        for (int k = 0; k < 16; ++k) {                                    \
            p += CUR[k];                                                  \
            const float w = (k < 15) ? (PREV[k + 1] + p) : p;             \
            __builtin_nontemporal_store(-0.2f * __logf(w),                \
                dst + (size_t)((tb) + k) * DD);                           \
        }                                                                 \
    }

__global__ __launch_bounds__(256, 4) void always_minish_v8(
    const float* __restrict__ lower,
    const float* __restrict__ upper,
    float* __restrict__ out)
{
    const int lane  = threadIdx.x & 63;                      // channel d
    const int wv    = (blockIdx.x << 2) | (threadIdx.x >> 6);
    const int seq   = wv >> 7;             // 0..31 = trace*16 + b
    const int strip = wv & (STRIPS - 1);   // 0..127
    const int tr    = seq >> 4;
    const int b     = seq & 15;

    const float* __restrict__ src =
        (tr ? upper : lower) + (size_t)b * TT * DD + lane;
    float* __restrict__ dst = out + (size_t)seq * TT * DD + lane;

    const int t0 = strip * SLEN;

    float H[16], X[16], Y[16], Z[16];

    // Halo t0-16..t0-1 (clamped to 0 == h0 broadcast semantics).
    #pragma unroll
    for (int j = 0; j < 16; ++j) {
        int t = t0 - 16 + j;
        if (t < 0) t = 0;
        H[j] = src[(size_t)t * DD];
    }
    // Blocks 0 and 1 raw.
    #pragma unroll
    for (int k = 0; k < 16; ++k) X[k] = src[(size_t)(t0 + k) * DD];
    #pragma unroll
    for (int k = 0; k < 16; ++k) Y[k] = src[(size_t)(t0 + 16 + k) * DD];

    // e_prev = exp(-5 * halo)
    #pragma unroll
    for (int j = 0; j < 16; ++j) H[j] = __expf(-5.0f * H[j]);

    // Block 0: prefetch block 2 -> Z (independent; issues under compute).
    #pragma unroll
    for (int k = 0; k < 16; ++k) Z[k] = src[(size_t)(t0 + 32 + k) * DD];
    BLOCK(H, X, t0);

    // Block 1: H is dead after block 0's suffix -> reuse for block 3.
    #pragma unroll
    for (int k = 0; k < 16; ++k) H[k] = src[(size_t)(t0 + 48 + k) * DD];
    BLOCK(X, Y, t0 + 16);

    // Blocks 2 and 3 (no more loads for this strip).
    BLOCK(Y, Z, t0 + 32);
    BLOCK(Z, H, t0 + 48);
}

extern "C" void kernel_launch(void* const* d_in, const int* in_sizes, int n_in,
                              void* d_out, int out_size, void* d_ws, size_t ws_size,
                              hipStream_t stream)
{
    const float* lower = (const float*)d_in[0];
    const float* upper = (const float*)d_in[1];
    float* out = (float*)d_out;

    // 32 seq * 128 strips = 4096 waves -> 1024 blocks of 4 waves.
    // Block = 4 consecutive strips of one seq -> 64KB contiguous region.
    dim3 grid(1024), block(256);
    hipLaunchKernelGGL(always_minish_v8, grid, block, 0, stream,
                       lower, upper, out);
}